// Round 2
// baseline (462.723 us; speedup 1.0000x reference)
//
#include <hip/hip_runtime.h>
#include <stdint.h>

#define T_DIM   8192
#define IN_DIM  4096
#define OUT_DIM 4096
#define RANK    8

typedef int v4i __attribute__((ext_vector_type(4)));

__device__ __forceinline__ void async_copy16(const void* g, void* l) {
  __builtin_amdgcn_global_load_lds(
      (const __attribute__((address_space(1))) void*)g,
      (__attribute__((address_space(3))) void*)l, 16, 0, 0);
}

// ---------------------------------------------------------------------------
// Kernel 0: repack weight from int32 (harness uploads integer inputs as int32)
// to contiguous int8. 4 elements/thread.
// ---------------------------------------------------------------------------
__global__ __launch_bounds__(256) void pack_w(
    const int* __restrict__ w32, int8_t* __restrict__ w8)
{
  const int idx = blockIdx.x * 256 + threadIdx.x;
  const int4 v = ((const int4*)w32)[idx];
  char4 q;
  q.x = (signed char)v.x; q.y = (signed char)v.y;
  q.z = (signed char)v.z; q.w = (signed char)v.w;
  ((char4*)w8)[idx] = q;
}

// ---------------------------------------------------------------------------
// Kernel 1: per-row int8 quantization + xa = x @ lora_a^T  (rank 8)
// 1024 blocks x 512 threads; each block does 8 rows; lora_a cached in regs.
// ---------------------------------------------------------------------------
#define Q_ROWS 8
#define Q_THREADS 512

__global__ __launch_bounds__(Q_THREADS) void quant_lora_a(
    const float* __restrict__ x,       // [T, IN]
    const float* __restrict__ lora_a,  // [RANK, IN]
    int8_t* __restrict__ x_i8,         // [T, IN]
    float* __restrict__ x_scale,       // [T]
    float* __restrict__ xa)            // [T, RANK]
{
  const int tid = threadIdx.x;
  const int row0 = blockIdx.x * Q_ROWS;

  // cache lora_a: thread tid owns float4 chunks at indices c*512 + tid (c=0,1)
  float4 av[RANK][2];
#pragma unroll
  for (int r = 0; r < RANK; ++r)
#pragma unroll
    for (int c = 0; c < 2; ++c)
      av[r][c] = ((const float4*)(lora_a + (size_t)r * IN_DIM))[c * 512 + tid];

  __shared__ float red[8][12]; // [wave][amax, 8 dots]; padded

  for (int rr = 0; rr < Q_ROWS; ++rr) {
    const int row = row0 + rr;
    const float4* xr = (const float4*)(x + (size_t)row * IN_DIM);
    float4 xv[2];
#pragma unroll
    for (int c = 0; c < 2; ++c) xv[c] = xr[c * 512 + tid];

    float am = 0.f;
#pragma unroll
    for (int c = 0; c < 2; ++c)
      am = fmaxf(am, fmaxf(fmaxf(fabsf(xv[c].x), fabsf(xv[c].y)),
                           fmaxf(fabsf(xv[c].z), fabsf(xv[c].w))));
    float dots[RANK];
#pragma unroll
    for (int r = 0; r < RANK; ++r) {
      float s = 0.f;
#pragma unroll
      for (int c = 0; c < 2; ++c)
        s += xv[c].x * av[r][c].x + xv[c].y * av[r][c].y +
             xv[c].z * av[r][c].z + xv[c].w * av[r][c].w;
      dots[r] = s;
    }
    // wave-level reduce (64 lanes)
#pragma unroll
    for (int off = 32; off > 0; off >>= 1) {
      am = fmaxf(am, __shfl_xor(am, off, 64));
#pragma unroll
      for (int r = 0; r < RANK; ++r) dots[r] += __shfl_xor(dots[r], off, 64);
    }
    const int wave = tid >> 6;
    if ((tid & 63) == 0) {
      red[wave][0] = am;
#pragma unroll
      for (int r = 0; r < RANK; ++r) red[wave][1 + r] = dots[r];
    }
    __syncthreads();
    float amax = 0.f;
#pragma unroll
    for (int w = 0; w < 8; ++w) amax = fmaxf(amax, red[w][0]);
    const float scale = amax * (1.0f / 127.0f);
    const float inv = 1.0f / fmaxf(scale, 1e-12f);

    char4* qout = (char4*)(x_i8 + (size_t)row * IN_DIM);
#pragma unroll
    for (int c = 0; c < 2; ++c) {
      char4 q;
      q.x = (signed char)(int)rintf(xv[c].x * inv);
      q.y = (signed char)(int)rintf(xv[c].y * inv);
      q.z = (signed char)(int)rintf(xv[c].z * inv);
      q.w = (signed char)(int)rintf(xv[c].w * inv);
      qout[c * 512 + tid] = q;
    }
    if (tid == 0) x_scale[row] = scale;
    if (tid < RANK) {
      float d = 0.f;
#pragma unroll
      for (int w = 0; w < 8; ++w) d += red[w][1 + tid];
      xa[(size_t)row * RANK + tid] = d;
    }
    __syncthreads();
  }
}

// ---------------------------------------------------------------------------
// Kernel 2: C = dequant(x_i8 @ W^T) + xa @ lora_b^T
// m97-style: BM=BN=128, BK=64, 256 thr (4 waves, 2x2), mfma_i32_16x16x64_i8,
// global_load_lds width=16 for both tiles.
// ---------------------------------------------------------------------------
__global__ __launch_bounds__(256) void int8_gemm_lora(
    const int8_t* __restrict__ A,       // x_i8 [T, IN]
    const int8_t* __restrict__ B,       // weight_i8 packed [OUT, IN]
    const float* __restrict__ x_scale,  // [T]
    const float* __restrict__ w_scale,  // [OUT]
    const float* __restrict__ xa,       // [T, RANK]
    const float* __restrict__ lora_b,   // [OUT, RANK]
    float* __restrict__ out)            // [T, OUT]
{
  __shared__ __align__(16) int8_t As[128 * 64]; // [row][k], 64B rows
  __shared__ __align__(16) int8_t Bs[128 * 64];
  __shared__ float xs_s[128];
  __shared__ float ws_s[128];
  __shared__ __align__(16) float xa_s[128 * RANK];
  __shared__ __align__(16) float lb_s[128 * RANK];

  const int tid = threadIdx.x;
  const int bx = blockIdx.x & 31;  // OUT_DIM/128 = 32 tiles
  const int by = blockIdx.x >> 5;  // T_DIM/128   = 64 tiles
  const size_t arow0 = (size_t)by * 128;
  const size_t brow0 = (size_t)bx * 128;

  // stage epilogue data (read only after K-loop barriers)
  if (tid < 128) xs_s[tid] = x_scale[arow0 + tid];
  else           ws_s[tid - 128] = w_scale[brow0 + (tid - 128)];
  ((float4*)xa_s)[tid] = ((const float4*)(xa + arow0 * RANK))[tid];
  ((float4*)lb_s)[tid] = ((const float4*)(lora_b + brow0 * RANK))[tid];

  v4i acc[4][4];
  const v4i vzero = {0, 0, 0, 0};
#pragma unroll
  for (int i = 0; i < 4; ++i)
#pragma unroll
    for (int j = 0; j < 4; ++j) acc[i][j] = vzero;

  const int lane = tid & 63;
  const int wave = tid >> 6;
  const int wr = wave >> 1, wc = wave & 1;
  const int quad = lane >> 4, m16 = lane & 15;

  // LDS fragment bases: A[m=lane&15][k=quad*16+j] (ds_read_b128)
  const int8_t* a_frag_base = As + ((wr * 64 + m16) * 64 + quad * 16);
  const int8_t* b_frag_base = Bs + ((wc * 64 + m16) * 64 + quad * 16);

  // staging: thread tid covers LDS bytes [tid*16, +16) and [4096+tid*16, +16)
  const int off0 = tid * 16;
  const int r0 = tid >> 2;          // LDS row for chunk 0
  const int c0 = (tid & 3) * 16;    // k-byte offset within row
  const int8_t* a_src = A + (arow0 + (size_t)r0) * IN_DIM + c0;
  const int8_t* b_src = B + (brow0 + (size_t)r0) * IN_DIM + c0;

  for (int k0 = 0; k0 < IN_DIM; k0 += 64) {
    async_copy16(a_src + k0,                         As + off0);
    async_copy16(a_src + (size_t)64 * IN_DIM + k0,   As + 4096 + off0);
    async_copy16(b_src + k0,                         Bs + off0);
    async_copy16(b_src + (size_t)64 * IN_DIM + k0,   Bs + 4096 + off0);
    __syncthreads();  // drains vmcnt(0) -> tiles complete

    v4i aF[4], bF[4];
#pragma unroll
    for (int i = 0; i < 4; ++i) aF[i] = *(const v4i*)(a_frag_base + i * 16 * 64);
#pragma unroll
    for (int j = 0; j < 4; ++j) bF[j] = *(const v4i*)(b_frag_base + j * 16 * 64);
#pragma unroll
    for (int i = 0; i < 4; ++i)
#pragma unroll
      for (int j = 0; j < 4; ++j)
        acc[i][j] = __builtin_amdgcn_mfma_i32_16x16x64_i8(aF[i], bF[j], acc[i][j], 0, 0, 0);
    __syncthreads();  // before next staging overwrites tiles
  }

  // Epilogue: dequant + rank-8 LoRA add, then store.
  float wscv[4];
  float4 lb0[4], lb1[4];
  int cols[4];
#pragma unroll
  for (int j = 0; j < 4; ++j) {
    const int c = wc * 64 + j * 16 + m16;
    cols[j] = c;
    wscv[j] = ws_s[c];
    lb0[j] = *(const float4*)(lb_s + c * RANK);
    lb1[j] = *(const float4*)(lb_s + c * RANK + 4);
  }
#pragma unroll
  for (int i = 0; i < 4; ++i) {
#pragma unroll
    for (int reg = 0; reg < 4; ++reg) {
      const int r = wr * 64 + i * 16 + quad * 4 + reg;
      const float xsc = xs_s[r];
      const float4 xa0 = *(const float4*)(xa_s + r * RANK);
      const float4 xa1 = *(const float4*)(xa_s + r * RANK + 4);
      float* orow = out + (arow0 + (size_t)r) * OUT_DIM + brow0;
#pragma unroll
      for (int j = 0; j < 4; ++j) {
        float v = (float)acc[i][j][reg] * xsc * wscv[j];
        v += xa0.x * lb0[j].x + xa0.y * lb0[j].y + xa0.z * lb0[j].z + xa0.w * lb0[j].w +
             xa1.x * lb1[j].x + xa1.y * lb1[j].y + xa1.z * lb1[j].z + xa1.w * lb1[j].w;
        orow[cols[j]] = v;
      }
    }
  }
}

// ---------------------------------------------------------------------------
extern "C" void kernel_launch(void* const* d_in, const int* in_sizes, int n_in,
                              void* d_out, int out_size, void* d_ws, size_t ws_size,
                              hipStream_t stream) {
  const float*  x        = (const float*)d_in[0];
  const int*    w_i32    = (const int*)d_in[1];    // integer input uploads as int32!
  const float*  w_scale  = (const float*)d_in[2];
  const float*  lora_a   = (const float*)d_in[3];
  const float*  lora_b   = (const float*)d_in[4];
  float* out = (float*)d_out;

  // workspace layout: x_i8 [T*IN] | w8 [OUT*IN] | x_scale [T] | xa [T*RANK]
  int8_t* x_i8   = (int8_t*)d_ws;
  int8_t* w8     = x_i8 + (size_t)T_DIM * IN_DIM;
  float* x_scale = (float*)(w8 + (size_t)OUT_DIM * IN_DIM);
  float* xa      = x_scale + T_DIM;

  pack_w<<<(OUT_DIM * IN_DIM / 4) / 256, 256, 0, stream>>>(w_i32, w8);
  quant_lora_a<<<T_DIM / Q_ROWS, Q_THREADS, 0, stream>>>(x, lora_a, x_i8, x_scale, xa);
  int8_gemm_lora<<<(T_DIM / 128) * (OUT_DIM / 128), 256, 0, stream>>>(
      x_i8, w8, x_scale, w_scale, xa, lora_b, out);
}